// Round 1
// baseline (275.840 us; speedup 1.0000x reference)
//
#include <hip/hip_runtime.h>
#include <stdint.h>

typedef __attribute__((ext_vector_type(8))) short bf16x8;
typedef __attribute__((ext_vector_type(4))) float f32x4;

namespace {
constexpr double CBRT2 = 1.2599210498948731647672106072782;
constexpr double W1 = 1.0 / (2.0 - CBRT2);
constexpr double W0 = -CBRT2 / (2.0 - CBRT2);
constexpr double DT = 0.01;
constexpr float DD1 = (float)(W1 * DT);
constexpr float DD2 = (float)(W0 * DT);
constexpr float DD3 = (float)(W1 * DT);
constexpr float CC1 = (float)(W1 / 2.0 * DT);
constexpr float CC2 = (float)((W0 + W1) / 2.0 * DT);
constexpr float CC3 = CC2;
constexpr float CC4 = CC1;
}

__device__ __forceinline__ short f2bf(float f) {
    uint32_t u = __builtin_bit_cast(uint32_t, f);
    u += 0x7fffu + ((u >> 16) & 1u);   // round-to-nearest-even
    return (short)(u >> 16);
}

// One wave owns 16 rows. State (v, force, x-accum) lives in registers in the
// MFMA C/D layout: element (t,i) <-> row = quad*4+i, col = (lane&15)+16*t.
// Per-wave private LDS: vbuf [16][64] bf16 (XOR-swizzled) for the v->A-frag
// transpose, h2buf [16][32] bf16 (k>=16 zeroed once) for the h2->A-frag
// transpose with K padded to 32. No cross-wave communication -> no barriers.
__global__ __launch_bounds__(256, 2)
void yoshida_mfma(const float* __restrict__ xin, const float* __restrict__ vin,
                  const float* __restrict__ fin, const float* __restrict__ Uin,
                  const float* __restrict__ Win,
                  float* __restrict__ xout, float* __restrict__ vout)
{
    const int tid  = threadIdx.x;
    const int lane = tid & 63;
    const int wave = tid >> 6;
    const int quad = lane >> 4;
    const int c16  = lane & 15;

    __shared__ alignas(16) char lds_all[4 * 3072];
    char* const vbuf  = lds_all + wave * 3072;   // [16][64] bf16, swizzled
    char* const h2buf = vbuf + 2048;             // [16][32] bf16

    // zero the k=16..31 pad of h2buf (written once, never touched again)
    *(uint64_t*)(h2buf + (lane >> 2) * 64 + 32 + (lane & 3) * 8) = 0ull;

    // ---- constant B-fragments (k-slot convention matches A reads) ----
    bf16x8 ufrag[2];
#pragma unroll
    for (int kt = 0; kt < 2; ++kt)
#pragma unroll
        for (int e = 0; e < 8; ++e) {
            const int k = kt * 32 + quad * 8 + e;
            ufrag[kt][e] = f2bf(Uin[k * 16 + c16]);
        }
    bf16x8 wfrag[4];
#pragma unroll
    for (int t = 0; t < 4; ++t)
#pragma unroll
        for (int e = 0; e < 8; ++e) {
            const int k = quad * 8 + e;
            wfrag[t][e] = (k < 16) ? f2bf(Win[k * 64 + t * 16 + c16]) : (short)0;
        }

    const int row_base = blockIdx.x * 64 + wave * 16;

    float vr[4][4], fr[4][4], xa[4][4];
#pragma unroll
    for (int t = 0; t < 4; ++t)
#pragma unroll
        for (int i = 0; i < 4; ++i) {
            const int g = (row_base + quad * 4 + i) * 64 + c16 + 16 * t;
            vr[t][i] = vin[g];
            fr[t][i] = fin[g];
            xa[t][i] = CC1 * vr[t][i];   // x1 term uses the original v
        }

    auto stage = [&](float DD, float CCn) {
        // v (C-layout f32 regs) -> bf16 -> vbuf [row m][k], XOR-swizzled
#pragma unroll
        for (int t = 0; t < 4; ++t)
#pragma unroll
            for (int i = 0; i < 4; ++i) {
                const int m   = quad * 4 + i;
                const int off = ((m << 7) + ((c16 + 16 * t) << 1)) ^ ((m & 7) << 4);
                *(short*)(vbuf + off) = f2bf(vr[t][i]);
            }
        // A-fragments: lane reads row c16, k = kt*32 + quad*8 .. +7 (16B)
        const int abase = (c16 << 7) + (quad << 4);
        const int swz   = (c16 & 7) << 4;
        const bf16x8 a0 = *(const bf16x8*)(vbuf + ((abase + 0)  ^ swz));
        const bf16x8 a1 = *(const bf16x8*)(vbuf + ((abase + 64) ^ swz));

        f32x4 h = {0.f, 0.f, 0.f, 0.f};
        h = __builtin_amdgcn_mfma_f32_16x16x32_bf16(a0, ufrag[0], h, 0, 0, 0);
        h = __builtin_amdgcn_mfma_f32_16x16x32_bf16(a1, ufrag[1], h, 0, 0, 0);

        // h2 = h*h (C layout) -> h2buf [m][r] bf16
#pragma unroll
        for (int i = 0; i < 4; ++i) {
            const int m = quad * 4 + i;
            *(short*)(h2buf + m * 64 + c16 * 2) = f2bf(h[i] * h[i]);
        }
        const bf16x8 a2 = *(const bf16x8*)(h2buf + c16 * 64 + quad * 16);

        // Gamma = h2 @ W  (4 col-tiles, K padded to 32), fused v/x update
#pragma unroll
        for (int t = 0; t < 4; ++t) {
            f32x4 gam = {0.f, 0.f, 0.f, 0.f};
            gam = __builtin_amdgcn_mfma_f32_16x16x32_bf16(a2, wfrag[t], gam, 0, 0, 0);
#pragma unroll
            for (int i = 0; i < 4; ++i) {
                vr[t][i] += DD * (fr[t][i] - gam[i]);   // a = force - Gamma
                xa[t][i] += CCn * vr[t][i];
            }
        }
    };

    stage(DD1, CC2);
    stage(DD2, CC3);
    stage(DD3, CC4);

#pragma unroll
    for (int t = 0; t < 4; ++t)
#pragma unroll
        for (int i = 0; i < 4; ++i) {
            const int g = (row_base + quad * 4 + i) * 64 + c16 + 16 * t;
            vout[g] = vr[t][i];
            xout[g] = xin[g] + xa[t][i];
        }
}

extern "C" void kernel_launch(void* const* d_in, const int* in_sizes, int n_in,
                              void* d_out, int out_size, void* d_ws, size_t ws_size,
                              hipStream_t stream) {
    const float* x = (const float*)d_in[0];
    const float* v = (const float*)d_in[1];
    const float* f = (const float*)d_in[2];
    const float* U = (const float*)d_in[3];
    const float* W = (const float*)d_in[4];
    const int BD = in_sizes[0];          // B*D = 67108864
    const int B  = BD / 64;
    float* xo = (float*)d_out;
    float* vo = (float*)d_out + BD;
    dim3 grid(B / 64);                   // 64 rows per 256-thread block
    yoshida_mfma<<<grid, 256, 0, stream>>>(x, v, f, U, W, xo, vo);
}